// Round 13
// baseline (4058.595 us; speedup 1.0000x reference)
//
#include <hip/hip_runtime.h>
#include <cstdint>
#include <cstddef>

using u8  = unsigned char;
using u16 = unsigned short;
using u32 = unsigned int;

typedef float f32x4 __attribute__((ext_vector_type(4)));
typedef u16 u16x4 __attribute__((ext_vector_type(4)));
typedef u32 u32x2 __attribute__((ext_vector_type(2)));
typedef u32 u32x4 __attribute__((ext_vector_type(4)));

#define DEV __device__ __forceinline__

constexpr float SS = 0.1f / 20.0f;    // STEP_SIZE = DT / N_STEPS
constexpr float WSC = 32.0f;          // weight pre-scale (dodges e4m3 denormals)
constexpr float WINV = 1.0f / 32.0f;  // folded back in epilogue

DEV float sigm(float x) { return 1.0f / (1.0f + __expf(-x)); }

DEV u16 f2bf(float f) {  // round-to-nearest-even f32 -> bf16
  union { float f; u32 u; } v; v.f = f;
  u32 r = v.u + 0x7FFFu + ((v.u >> 16) & 1u);
  return (u16)(r >> 16);
}
DEV float bf2f(u16 h) {
  union { u32 u; float f; } v; v.u = ((u32)h) << 16;
  return v.f;
}
DEV u32 pk4_fp8(float a, float b, float c, float d) {  // 4 f32 -> 4 fp8 bytes
  u32 r = (u32)__builtin_amdgcn_cvt_pk_fp8_f32(a, b, 0, false);
  r = (u32)__builtin_amdgcn_cvt_pk_fp8_f32(c, d, (int)r, true);
  return r;
}

// ---------------------------------------------------------------------------
// prep: f32 copy / sigmoid f32 (s3 path only)
// ---------------------------------------------------------------------------
__global__ void k_prep(const float* __restrict__ in, float* __restrict__ fcopy,
                       float* __restrict__ sigf32, int n) {
  int stride = gridDim.x * blockDim.x;
  for (int i = blockIdx.x * blockDim.x + threadIdx.x; i < n; i += stride) {
    float v = in[i];
    if (fcopy) fcopy[i] = v;
    if (sigf32) sigf32[i] = sigm(v);
  }
}

// fp8 encode, 4 elems/thread: optional sigmoid, else scale
__global__ void k_prep8(const float* __restrict__ in, u8* __restrict__ out,
                        int n4, int dosig, float scale) {
  int stride = gridDim.x * blockDim.x;
  for (int i = blockIdx.x * blockDim.x + threadIdx.x; i < n4; i += stride) {
    f32x4 v = *(const f32x4*)(in + (size_t)i * 4);
    float a, b, c, d;
    if (dosig) { a = sigm(v[0]); b = sigm(v[1]); c = sigm(v[2]); d = sigm(v[3]); }
    else       { a = v[0] * scale; b = v[1] * scale; c = v[2] * scale; d = v[3] * scale; }
    *(u32*)(out + (size_t)i * 4) = pk4_fp8(a, b, c, d);
  }
}

// out[n][k] = fp8(in[k][n] * scale);  in: K x N f32
__global__ void k_transpose_fp8(const float* __restrict__ in, u8* __restrict__ out,
                                int K, int N, float scale) {
  __shared__ float tile[32][33];
  int kb = blockIdx.x * 32, nb = blockIdx.y * 32;
  int tx = threadIdx.x & 31, ty = threadIdx.x >> 5;  // 256 threads: 32x8
#pragma unroll
  for (int i = 0; i < 4; ++i)
    tile[ty + 8 * i][tx] = in[(size_t)(kb + ty + 8 * i) * N + nb + tx];
  __syncthreads();
  if (tx < 8) {
#pragma unroll
    for (int i = 0; i < 4; ++i) {
      int orow = nb + ty + 8 * i;
      u32 r = pk4_fp8(tile[tx * 4 + 0][ty + 8 * i] * scale,
                      tile[tx * 4 + 1][ty + 8 * i] * scale,
                      tile[tx * 4 + 2][ty + 8 * i] * scale,
                      tile[tx * 4 + 3][ty + 8 * i] * scale);
      *(u32*)(out + (size_t)orow * K + kb + tx * 4) = r;
    }
  }
}

// ---------------------------------------------------------------------------
// Geometry (R5): 128x128 tile, grid 32x16 = 512 blocks (2/CU), 512 threads.
// Wave grid 2(M) x 4(N); per-wave 64x32; acc[4][2].
//   gr = tm + (wid>>2)*64 + i*16 + (lane&15)
//   gc = tn + (wid&3)*32 + j*16 + 4*(lane>>4) + rr
// Swizzle-resident buffers (statef, addcb): [blk][k=i*2+j][tid][x4].
// ---------------------------------------------------------------------------
DEV void tile_base(int b, int& tm, int& tn) {
  int xcd = b & 7, slot = b >> 3;           // XCD-aware 2D chunking, grid 32x16
  tm = ((((xcd >> 1) << 3) | (slot >> 3))) * 128;  // 0..31
  tn = ((((xcd & 1) << 3) | (slot & 7))) * 128;    // 0..15
}

__global__ void k_init_state(const float* __restrict__ src, float* __restrict__ dst_swz) {
  int b = blockIdx.x;
  int tm, tn; tile_base(b, tm, tn);
  int tid = threadIdx.x, lane = tid & 63, wid = tid >> 6;
  int l15 = lane & 15, lhi = lane >> 4;
  int wm = (wid >> 2) * 64, wn = (wid & 3) * 32;
#pragma unroll
  for (int i = 0; i < 4; ++i)
#pragma unroll
    for (int j = 0; j < 2; ++j) {
      int gr = tm + wm + i * 16 + l15;
      int gc0 = tn + wn + j * 16 + 4 * lhi;
      f32x4 v = *(const f32x4*)(src + (size_t)gr * 2048 + gc0);
      *(f32x4*)(dst_swz + (((size_t)b * 8 + i * 2 + j) * 512 + tid) * 4) = v;
    }
}

// ---------------------------------------------------------------------------
// FP8 GEMM (R5 schedule, byte-identical ledger): C = A(MxK fp8 rm) * Bt^T
// (Bt = N x K fp8 rm, pre-scaled x32). 128x128 tile, BK=128 ELEMENTS = 128 B
// per row (same staging bytes as bf16 BK=64), nt = K/128 (16 or 8) -> half
// the barriers of R5. 16x16x32_fp8_fp8 MFMA SWAPPED (mfma(b,a)): lane=C-row,
// regs=4 C-cols; per phase 4 K-slices x 8 MFMA. LDS XOR-swizzle both-sides
// on 16B slots (8/row, ^row&7 — same as R5). Counted vmcnt(4), dbuf.
// acc carries x32 from B — epilogue multiplies WINV.
// sigb output (fp8, 4B/lane) is REPACKED through LDS (128x144 tile over the
// staging LDS, post-loop, barrier-guarded) into 16B/lane coalesced stores.
// MODE 0: addcb_swz = bf16(acc*WINV + bias[gc])        (loop-invariant term)
// MODE 1: pre = acc*WINV + bf2f(addcb); update -> statef_swz, sig8(rm fp8)
// MODE 2: pre = acc*WINV + bias + sum_k sig3[gr][k]*w2[gc*10+k]; update
// ---------------------------------------------------------------------------
template <int MODE>
__launch_bounds__(512, 4)
__global__ void k_gemm(const u8* __restrict__ A, const u8* __restrict__ Bt,
                       int N, int K,
                       const u16* __restrict__ addcb, const float* __restrict__ bias,
                       const float* __restrict__ sig3, const float* __restrict__ w2,
                       float* __restrict__ statef, u16* __restrict__ sigb16,
                       u8* __restrict__ sig8) {
  __shared__ __align__(16) u8 lds8[65536];
  u8* const Als0 = lds8;            // 16 KB
  u8* const Als1 = lds8 + 16384;    // 16 KB
  u8* const Bls0 = lds8 + 32768;    // 16 KB
  u8* const Bls1 = lds8 + 49152;    // 16 KB

  int b = blockIdx.x;
  int tm, tn; tile_base(b, tm, tn);
  int tid = threadIdx.x;
  int lane = tid & 63, wid = tid >> 6;
  int l15 = lane & 15, lhi = lane >> 4;
  int wm = (wid >> 2) * 64, wn = (wid & 3) * 32;

  const u8* Ag = A + (size_t)tm * K;
  const u8* Bg = Bt + (size_t)tn * K;

  f32x4 acc[4][2] = {};

  // 4 gload_lds per call (the vmcnt unit — same as R5)
  auto stage = [&](int buf, int t) {
    u8* Ap = buf ? Als1 : Als0;
    u8* Bp = buf ? Bls1 : Bls0;
    int k0 = t * 128;
#pragma unroll
    for (int rd = 0; rd < 2; ++rd) {
      int S = rd * 512 + tid;              // 16B slot 0..1023
      int row = S >> 3;                    // 8 slots (128B) per row
      int cs = ((S & 7) ^ (row & 7)) * 16; // pre-swizzled global byte col
      __builtin_amdgcn_global_load_lds(
          (const __attribute__((address_space(1))) u32*)(Ag + (size_t)row * K + k0 + cs),
          (__attribute__((address_space(3))) u32*)(Ap + S * 16), 16, 0, 0);
      __builtin_amdgcn_global_load_lds(
          (const __attribute__((address_space(1))) u32*)(Bg + (size_t)row * K + k0 + cs),
          (__attribute__((address_space(3))) u32*)(Bp + S * 16), 16, 0, 0);
    }
  };

  auto compute = [&](int buf) {
    const u8* Ap = buf ? Als1 : Als0;
    const u8* Bp = buf ? Bls1 : Bls0;
    int sub = (lhi & 1) * 8;
    __builtin_amdgcn_s_setprio(1);
#pragma unroll
    for (int s = 0; s < 4; ++s) {           // 4 K=32 slices per BK=128
      int so = s * 2 + (lhi >> 1);          // 16B slot of this 8B fragment
      u32x2 af[4], bfr[2];
#pragma unroll
      for (int i = 0; i < 4; ++i) {
        int row = wm + i * 16 + l15;
        af[i] = *(const u32x2*)(Ap + row * 128 + ((so ^ (row & 7)) * 16) + sub);
      }
#pragma unroll
      for (int j = 0; j < 2; ++j) {
        int row = wn + j * 16 + l15;
        bfr[j] = *(const u32x2*)(Bp + row * 128 + ((so ^ (row & 7)) * 16) + sub);
      }
#pragma unroll
      for (int i = 0; i < 4; ++i)
#pragma unroll
        for (int j = 0; j < 2; ++j)         // SWAPPED operands
          acc[i][j] = __builtin_amdgcn_mfma_f32_16x16x32_fp8_fp8(
              __builtin_bit_cast(long, bfr[j]), __builtin_bit_cast(long, af[i]),
              acc[i][j], 0, 0, 0);
    }
    __builtin_amdgcn_s_setprio(0);
  };

  // --- counted-vmcnt depth-2 pipeline (R5 ledger); nt even (16 or 8) ---
  const int nt = K / 128;
  stage(0, 0);
  stage(1, 1);
  asm volatile("s_waitcnt vmcnt(4)" ::: "memory");  // tile 0 landed
  __builtin_amdgcn_s_barrier();
  asm volatile("" ::: "memory");

  int t = 0;
  for (; t + 3 < nt; t += 2) {
    compute(0);
    asm volatile("" ::: "memory");
    __builtin_amdgcn_s_barrier();
    asm volatile("" ::: "memory");
    stage(0, t + 2);
    asm volatile("s_waitcnt vmcnt(4)" ::: "memory");
    __builtin_amdgcn_s_barrier();
    asm volatile("" ::: "memory");

    compute(1);
    asm volatile("" ::: "memory");
    __builtin_amdgcn_s_barrier();
    asm volatile("" ::: "memory");
    stage(1, t + 3);
    asm volatile("s_waitcnt vmcnt(4)" ::: "memory");
    __builtin_amdgcn_s_barrier();
    asm volatile("" ::: "memory");
  }
  compute(0);
  asm volatile("s_waitcnt vmcnt(0)" ::: "memory");
  __builtin_amdgcn_s_barrier();
  asm volatile("" ::: "memory");
  compute(1);

  // Epilogue. acc[i][j][rr] = 32 * C[tm+wm+i*16+l15][tn+wn+j*16+4*lhi+rr]
  if constexpr (MODE == 0) {
#pragma unroll
    for (int i = 0; i < 4; ++i)
#pragma unroll
      for (int j = 0; j < 2; ++j) {
        int gc0 = tn + wn + j * 16 + 4 * lhi;
        size_t sidx = (((size_t)b * 8 + i * 2 + j) * 512 + tid) * 4;
        u16x4 sb;
#pragma unroll
        for (int rr = 0; rr < 4; ++rr)
          sb[rr] = f2bf(acc[i][j][rr] * WINV + bias[gc0 + rr]);
        *(u16x4*)(sigb16 + sidx) = sb;
      }
  } else {
    // all K-loop LDS reads are done per-wave; barrier before overlaying T
    asm volatile("" ::: "memory");
    __builtin_amdgcn_s_barrier();
    asm volatile("" ::: "memory");
    u8* T = lds8;  // 128 x 144 repack tile (16B-aligned rows)
#pragma unroll
    for (int i = 0; i < 4; ++i)
#pragma unroll
      for (int j = 0; j < 2; ++j) {
        size_t sidx = (((size_t)b * 8 + i * 2 + j) * 512 + tid) * 4;
        f32x4 old = *(const f32x4*)(statef + sidx);
        f32x4 nv; float sv[4];
#pragma unroll
        for (int rr = 0; rr < 4; ++rr) {
          float pre = acc[i][j][rr] * WINV;
          if constexpr (MODE == 1) {
            u16x4 ab = *(const u16x4*)(addcb + sidx);
            pre += bf2f(ab[rr]);
          } else {
            int gc = tn + wn + j * 16 + 4 * lhi + rr;
            float ex = bias[gc];
            int gr = tm + wm + i * 16 + l15;
#pragma unroll
            for (int k = 0; k < 10; ++k) ex += sig3[gr * 10 + k] * w2[gc * 10 + k];
            pre += ex;
          }
          float o = old[rr];
          float sg = sigm(o);
          float n = o - SS * (sg * (1.0f - sg) * pre - o);
          nv[rr] = n; sv[rr] = sigm(n);
        }
        *(f32x4*)(statef + sidx) = nv;
        int grl = wm + i * 16 + l15;
        int gcl = wn + j * 16 + 4 * lhi;
        *(u32*)(T + grl * 144 + gcl) = pk4_fp8(sv[0], sv[1], sv[2], sv[3]);
      }
    asm volatile("s_waitcnt lgkmcnt(0)" ::: "memory");
    __builtin_amdgcn_s_barrier();
    asm volatile("" ::: "memory");
#pragma unroll
    for (int rd = 0; rd < 2; ++rd) {
      int S = rd * 512 + tid;
      int r = S >> 3, c = S & 7;
      u32x4 v = *(const u32x4*)(T + r * 144 + c * 16);
      *(u32x4*)(sig8 + (size_t)(tm + r) * N + tn + c * 16) = v;
    }
  }
}

// ---------------------------------------------------------------------------
// output-layer update: pre[m][n] = sum_k sig(s2)[m][k]*w2[k*10+n] + b2[n]
// fp8 input, HW decode; 16 rows/block, 16 lanes/row, shuffle-reduce.
// ---------------------------------------------------------------------------
__global__ void k_out(const u8* __restrict__ sigs2b8, const float* __restrict__ w2,
                      const float* __restrict__ b2, float* __restrict__ s3f,
                      float* __restrict__ sigs3f, float* __restrict__ outOrNull) {
  int tid = threadIdx.x;
  int r = tid >> 4, l16 = tid & 15;
  int row = blockIdx.x * 16 + r;
  float acc[10] = {};
  const u32x4* arow = (const u32x4*)(sigs2b8 + (size_t)row * 2048);
  for (int kb = l16; kb < 128; kb += 16) {  // 16B = 16 fp8 per chunk
    u32x4 v = arow[kb];
#pragma unroll
    for (int w = 0; w < 4; ++w) {
      const float* wr = w2 + (size_t)(kb * 16 + w * 4) * 10;
      float f0 = __builtin_amdgcn_cvt_f32_fp8((int)v[w], 0);
      float f1 = __builtin_amdgcn_cvt_f32_fp8((int)v[w], 1);
      float f2 = __builtin_amdgcn_cvt_f32_fp8((int)v[w], 2);
      float f3 = __builtin_amdgcn_cvt_f32_fp8((int)v[w], 3);
#pragma unroll
      for (int n = 0; n < 10; ++n)
        acc[n] += f0 * wr[n] + f1 * wr[10 + n] + f2 * wr[20 + n] + f3 * wr[30 + n];
    }
  }
#pragma unroll
  for (int m = 1; m < 16; m <<= 1)
#pragma unroll
    for (int n = 0; n < 10; ++n) acc[n] += __shfl_xor(acc[n], m, 64);
  if (l16 < 10) {
    float pre = 0.0f;
#pragma unroll
    for (int n = 0; n < 10; ++n)
      if (l16 == n) pre = acc[n];
    pre += b2[l16];
    size_t idx = (size_t)row * 10 + l16;
    float old = s3f[idx];
    float sg = sigm(old);
    float nv = old - SS * (sg * (1.0f - sg) * pre - old);
    s3f[idx] = nv;
    sigs3f[idx] = sigm(nv);
    if (outOrNull) outOrNull[idx] = nv;
  }
}

// ---------------------------------------------------------------------------
extern "C" void kernel_launch(void* const* d_in, const int* in_sizes, int n_in,
                              void* d_out, int out_size, void* d_ws, size_t ws_size,
                              hipStream_t stream) {
  const float* x  = (const float*)d_in[0];
  const float* w0 = (const float*)d_in[1];  // 1024 x 2048
  const float* w1 = (const float*)d_in[2];  // 2048 x 2048
  const float* w2 = (const float*)d_in[3];  // 2048 x 10
  const float* b0 = (const float*)d_in[4];
  const float* b1 = (const float*)d_in[5];
  const float* b2 = (const float*)d_in[6];
  const float* s1 = (const float*)d_in[7];
  const float* s2 = (const float*)d_in[8];
  const float* s3 = (const float*)d_in[9];
  float* out = (float*)d_out;

  uint8_t* p = (uint8_t*)d_ws;
  auto alloc = [&](size_t bytes) {
    uint8_t* r = p;
    p += (bytes + 255) & ~(size_t)255;
    return r;
  };
  float* s1f    = (float*)alloc(4096ull * 2048 * 4);  // swizzle-resident f32
  float* s2f    = (float*)alloc(4096ull * 2048 * 4);  // swizzle-resident f32
  u16*   addcb  = (u16*)alloc(4096ull * 2048 * 2);    // swizzle-resident bf16
  u8*    sigs1b = (u8*)alloc(4096ull * 2048);         // row-major fp8
  u8*    sigs2b = (u8*)alloc(4096ull * 2048);         // row-major fp8
  u8*    sigxb  = (u8*)alloc(4096ull * 1024);         // fp8
  u8*    w1b    = (u8*)alloc(2048ull * 2048);         // Bt for B=w1^T (fp8 x32)
  u8*    w1tb   = (u8*)alloc(2048ull * 2048);         // Bt for B=w1   (fp8 x32)
  u8*    w0tb   = (u8*)alloc(2048ull * 1024);         // Bt for B=w0   (fp8 x32)
  float* s3f    = (float*)alloc(4096ull * 10 * 4);
  float* sigs3f = (float*)alloc(4096ull * 10 * 4);
  (void)ws_size; (void)in_sizes; (void)n_in; (void)out_size;

  auto grid = [](int n) { int g = (n + 255) / 256; return g > 2048 ? 2048 : g; };

  // one-time prep (re-done every call: poison-safe, deterministic)
  k_prep8<<<grid(4096 * 1024 / 4), 256, 0, stream>>>(x, sigxb, 4096 * 1024 / 4, 1, 1.0f);
  k_prep8<<<grid(2048 * 2048 / 4), 256, 0, stream>>>(w1, w1b, 2048 * 2048 / 4, 0, WSC);
  k_prep8<<<grid(4096 * 2048 / 4), 256, 0, stream>>>(s2, sigs2b, 4096 * 2048 / 4, 1, 1.0f);
  k_prep<<<grid(40960), 256, 0, stream>>>(s3, s3f, sigs3f, 40960);
  k_init_state<<<512, 512, 0, stream>>>(s1, s1f);
  k_init_state<<<512, 512, 0, stream>>>(s2, s2f);
  k_transpose_fp8<<<dim3(1024 / 32, 2048 / 32), 256, 0, stream>>>(w0, w0tb, 1024, 2048, WSC);
  k_transpose_fp8<<<dim3(2048 / 32, 2048 / 32), 256, 0, stream>>>(w1, w1tb, 2048, 2048, WSC);

  // addcb = bf16(sig(x) @ w0 + b0)  (M=4096, N=2048, K=1024) — loop-invariant
  k_gemm<0><<<512, 512, 0, stream>>>(sigxb, w0tb, 2048, 1024,
                                     nullptr, b0, nullptr, nullptr,
                                     nullptr, addcb, nullptr);

  for (int t = 0; t < 20; ++t) {
    // s1 update: pre = (sigxw0 + b0) + sig(s2)@w1^T
    k_gemm<1><<<512, 512, 0, stream>>>(sigs2b, w1b, 2048, 2048,
                                       addcb, nullptr, nullptr, nullptr,
                                       s1f, nullptr, sigs1b);
    // s2 update: pre = sig(s1_new)@w1 + sig(s3)@w2^T + b1
    k_gemm<2><<<512, 512, 0, stream>>>(sigs1b, w1tb, 2048, 2048,
                                       nullptr, b1, sigs3f, w2,
                                       s2f, nullptr, sigs2b);
    // s3 update: pre = sig(s2_new)@w2 + b2
    k_out<<<256, 256, 0, stream>>>(sigs2b, w2, b2, s3f, sigs3f, (t == 19) ? out : nullptr);
  }
}

// Round 14
// 2507.634 us; speedup vs baseline: 1.6185x; 1.6185x over previous
//
#include <hip/hip_runtime.h>
#include <cstdint>
#include <cstddef>

using u16 = unsigned short;
using u32 = unsigned int;

typedef __bf16 bf16x8 __attribute__((ext_vector_type(8)));
typedef float f32x4 __attribute__((ext_vector_type(4)));
typedef u16 u16x4 __attribute__((ext_vector_type(4)));

#define DEV __device__ __forceinline__

constexpr float SS = 0.1f / 20.0f;  // STEP_SIZE = DT / N_STEPS

DEV float sigm(float x) { return 1.0f / (1.0f + __expf(-x)); }

DEV u16 f2bf(float f) {  // round-to-nearest-even f32 -> bf16
  union { float f; u32 u; } v; v.f = f;
  u32 r = v.u + 0x7FFFu + ((v.u >> 16) & 1u);
  return (u16)(r >> 16);
}
DEV float bf2f(u16 h) {
  union { u32 u; float f; } v; v.u = ((u32)h) << 16;
  return v.f;
}

// ---------------------------------------------------------------------------
// prep: optional sigmoid(f32) / sigmoid(bf16) / raw bf16 convert / f32 copy
// ---------------------------------------------------------------------------
__global__ void k_prep(const float* __restrict__ in, float* __restrict__ fcopy,
                       float* __restrict__ sigf32, u16* __restrict__ sigb,
                       u16* __restrict__ rawb, int n) {
  int stride = gridDim.x * blockDim.x;
  for (int i = blockIdx.x * blockDim.x + threadIdx.x; i < n; i += stride) {
    float v = in[i];
    if (fcopy) fcopy[i] = v;
    if (rawb) rawb[i] = f2bf(v);
    if (sigf32 || sigb) {
      float s = sigm(v);
      if (sigf32) sigf32[i] = s;
      if (sigb) sigb[i] = f2bf(s);
    }
  }
}

// out[n][k] = bf16(in[k][n]);  in: K x N f32, K,N multiples of 32
__global__ void k_transpose_bf16(const float* __restrict__ in, u16* __restrict__ out,
                                 int K, int N) {
  __shared__ float tile[32][33];
  int kb = blockIdx.x * 32, nb = blockIdx.y * 32;
  int tx = threadIdx.x & 31, ty = threadIdx.x >> 5;  // 256 threads: 32x8
#pragma unroll
  for (int i = 0; i < 4; ++i)
    tile[ty + 8 * i][tx] = in[(size_t)(kb + ty + 8 * i) * N + nb + tx];
  __syncthreads();
#pragma unroll
  for (int i = 0; i < 4; ++i)
    out[(size_t)(nb + ty + 8 * i) * K + kb + tx] = f2bf(tile[tx][ty + 8 * i]);
}

// ---------------------------------------------------------------------------
// Geometry: 128x128 tile, grid 32(M) x 16(N) = 512 blocks (2/CU), 512 thr.
// Wave grid 2(M) x 4(N); per-wave 64x32; acc[4][2].
//   gr = tm + (wid>>2)*64 + i*16 + (lane&15)
//   gc = tn + (wid&3)*32 + j*16 + 4*(lane>>4) + rr
// Swizzle-resident buffers (statef, addcb): [blk][k=i*2+j][tid][x4].
// ---------------------------------------------------------------------------
DEV void tile_base(int b, int& tm, int& tn) {
  int xcd = b & 7, slot = b >> 3;           // XCD-aware 2D chunking, grid 32x16
  tm = ((((xcd >> 1) << 3) | (slot >> 3))) * 128;  // 0..31
  tn = ((((xcd & 1) << 3) | (slot & 7))) * 128;    // 0..15
}

// init swizzle-resident state from a row-major M x 2048 f32 source
__global__ void k_init_state(const float* __restrict__ src, float* __restrict__ dst_swz) {
  int b = blockIdx.x;
  int tm, tn; tile_base(b, tm, tn);
  int tid = threadIdx.x, lane = tid & 63, wid = tid >> 6;
  int l15 = lane & 15, lhi = lane >> 4;
  int wm = (wid >> 2) * 64, wn = (wid & 3) * 32;
#pragma unroll
  for (int i = 0; i < 4; ++i)
#pragma unroll
    for (int j = 0; j < 2; ++j) {
      int gr = tm + wm + i * 16 + l15;
      int gc0 = tn + wn + j * 16 + 4 * lhi;
      f32x4 v = *(const f32x4*)(src + (size_t)gr * 2048 + gc0);
      *(f32x4*)(dst_swz + (((size_t)b * 8 + i * 2 + j) * 512 + tid) * 4) = v;
    }
}

// ---------------------------------------------------------------------------
// GEMM (champion R5 structure): C = A(MxK, bf16 rm) * Bt^T (Bt = N x K bf16
// rm). 128x128 tile, BK=64, 8 waves, 16x16x32 MFMA with SWAPPED operands
// (mfma(b,a)): lane = C-row, 4 acc regs = 4 consecutive C-cols ->
// float4/u16x4 epilogue. LDS XOR-swizzled both-sides (rule #21).
// Counted-vmcnt depth-2 pipeline:
//   compute(buf); barrier; stage(buf, t+2); vmcnt(4); barrier
// (4 = per-thread gload_lds per K-step; tile t+2 stays in flight).
// T5 setprio around MFMA cluster.
// MODE 0: addcb_swz = bf16(acc + bias[gc])             (loop-invariant term)
// MODE 1: pre = acc + bf2f(addcb_swz); update -> statef_swz, sigb(rm)
// MODE 2: pre = acc + bias + sum_k sig3[gr][k]*w2[gc*10+k]; update state
// ---------------------------------------------------------------------------
template <int MODE>
__launch_bounds__(512, 4)
__global__ void k_gemm(const u16* __restrict__ A, const u16* __restrict__ Bt,
                       int M, int N, int K,
                       const u16* __restrict__ addcb, const float* __restrict__ bias,
                       const float* __restrict__ sig3, const float* __restrict__ w2,
                       float* __restrict__ statef, u16* __restrict__ sigb) {
  constexpr int BM = 128, BN = 128, BK = 64;
  __shared__ __align__(16) u16 Als[2][BM * BK];
  __shared__ __align__(16) u16 Bls[2][BN * BK];
  int b = blockIdx.x;
  int tm, tn; tile_base(b, tm, tn);
  int tid = threadIdx.x;
  int lane = tid & 63, wid = tid >> 6;
  int l15 = lane & 15, lhi = lane >> 4;
  int wm = (wid >> 2) * 64, wn = (wid & 3) * 32;

  const u16* Ag = A + (size_t)tm * K;
  const u16* Bg = Bt + (size_t)tn * K;

  f32x4 acc[4][2] = {};

  // exactly 4 gload_lds per thread per call (the vmcnt unit)
  auto stage = [&](int buf, int k0) {
#pragma unroll
    for (int rd = 0; rd < 2; ++rd) {
      int S = rd * 512 + tid;              // 16B slot index, linear in LDS
      int row = S >> 3;                    // 8 slots (128B) per 64-elem row
      int cs = ((S & 7) ^ (row & 7)) * 8;  // pre-swizzled global column
      __builtin_amdgcn_global_load_lds(
          (const __attribute__((address_space(1))) u32*)(Ag + (size_t)row * K + k0 + cs),
          (__attribute__((address_space(3))) u32*)(&Als[buf][0] + S * 8), 16, 0, 0);
      __builtin_amdgcn_global_load_lds(
          (const __attribute__((address_space(1))) u32*)(Bg + (size_t)row * K + k0 + cs),
          (__attribute__((address_space(3))) u32*)(&Bls[buf][0] + S * 8), 16, 0, 0);
    }
  };

  auto compute = [&](int buf) {
    __builtin_amdgcn_s_setprio(1);
#pragma unroll
    for (int s = 0; s < 2; ++s) {
      bf16x8 af[4], bfr[2];
#pragma unroll
      for (int i = 0; i < 4; ++i) {
        int row = wm + i * 16 + l15;
        af[i] = *(const bf16x8*)(&Als[buf][0] + row * BK + (((s * 4 + lhi) ^ (row & 7)) * 8));
      }
#pragma unroll
      for (int j = 0; j < 2; ++j) {
        int row = wn + j * 16 + l15;
        bfr[j] = *(const bf16x8*)(&Bls[buf][0] + row * BK + (((s * 4 + lhi) ^ (row & 7)) * 8));
      }
#pragma unroll
      for (int i = 0; i < 4; ++i)
#pragma unroll
        for (int j = 0; j < 2; ++j)  // SWAPPED operands
          acc[i][j] = __builtin_amdgcn_mfma_f32_16x16x32_bf16(bfr[j], af[i], acc[i][j], 0, 0, 0);
    }
    __builtin_amdgcn_s_setprio(0);
  };

  // --- counted-vmcnt depth-2 pipeline; nt even (K/64 = 16 or 32) ---
  const int nt = K / BK;
  stage(0, 0);           // 4 outstanding (tile 0)
  stage(1, BK);          // 8 outstanding (tiles 0,1)
  asm volatile("s_waitcnt vmcnt(4)" ::: "memory");  // tile 0 landed
  __builtin_amdgcn_s_barrier();
  asm volatile("" ::: "memory");

  int t = 0;
  for (; t + 3 < nt; t += 2) {
    compute(0);                                      // reads tile t (buf0)
    asm volatile("" ::: "memory");
    __builtin_amdgcn_s_barrier();                    // all waves done reading buf0
    asm volatile("" ::: "memory");
    stage(0, (t + 2) * BK);                          // restage buf0 <- tile t+2
    asm volatile("s_waitcnt vmcnt(4)" ::: "memory"); // tile t+1 landed (t+2 in flight)
    __builtin_amdgcn_s_barrier();
    asm volatile("" ::: "memory");

    compute(1);                                      // reads tile t+1 (buf1)
    asm volatile("" ::: "memory");
    __builtin_amdgcn_s_barrier();
    asm volatile("" ::: "memory");
    stage(1, (t + 3) * BK);                          // restage buf1 <- tile t+3
    asm volatile("s_waitcnt vmcnt(4)" ::: "memory"); // tile t+2 landed
    __builtin_amdgcn_s_barrier();
    asm volatile("" ::: "memory");
  }
  // t == nt-2: buf0 holds tile nt-2 (ready), buf1's tile nt-1 loads outstanding
  compute(0);
  asm volatile("s_waitcnt vmcnt(0)" ::: "memory");   // drain tile nt-1
  __builtin_amdgcn_s_barrier();
  asm volatile("" ::: "memory");
  compute(1);

  // Epilogue. acc[i][j][rr] = C[tm+wm+i*16+l15][tn+wn+j*16+4*lhi+rr]
  // swizzle-resident index: (((b*8 + i*2+j)*512 + tid)*4 + rr)
  if constexpr (MODE == 0) {
#pragma unroll
    for (int i = 0; i < 4; ++i)
#pragma unroll
      for (int j = 0; j < 2; ++j) {
        int gc0 = tn + wn + j * 16 + 4 * lhi;
        size_t sidx = (((size_t)b * 8 + i * 2 + j) * 512 + tid) * 4;
        u16x4 sb;
#pragma unroll
        for (int rr = 0; rr < 4; ++rr) sb[rr] = f2bf(acc[i][j][rr] + bias[gc0 + rr]);
        *(u16x4*)(sigb + sidx) = sb;  // sigb arg doubles as addcb_swz output
      }
  } else if constexpr (MODE == 1) {
#pragma unroll
    for (int i = 0; i < 4; ++i)
#pragma unroll
      for (int j = 0; j < 2; ++j) {
        int gr = tm + wm + i * 16 + l15;
        int gc0 = tn + wn + j * 16 + 4 * lhi;
        size_t sidx = (((size_t)b * 8 + i * 2 + j) * 512 + tid) * 4;
        u16x4 ab = *(const u16x4*)(addcb + sidx);
        f32x4 old = *(const f32x4*)(statef + sidx);
        f32x4 nv; u16x4 sb;
#pragma unroll
        for (int rr = 0; rr < 4; ++rr) {
          float pre = acc[i][j][rr] + bf2f(ab[rr]);
          float o = old[rr];
          float sg = sigm(o);
          float n = o - SS * (sg * (1.0f - sg) * pre - o);
          nv[rr] = n; sb[rr] = f2bf(sigm(n));
        }
        *(f32x4*)(statef + sidx) = nv;
        *(u16x4*)(sigb + (size_t)gr * N + gc0) = sb;  // row-major (next GEMM's A)
      }
  } else {
    float s3v[4][10];
#pragma unroll
    for (int i = 0; i < 4; ++i) {
      int gr = tm + wm + i * 16 + l15;
#pragma unroll
      for (int k = 0; k < 10; ++k) s3v[i][k] = sig3[gr * 10 + k];
    }
#pragma unroll
    for (int j = 0; j < 2; ++j) {
      int gc0 = tn + wn + j * 16 + 4 * lhi;
      float wv[4][10]; f32x4 bb;
#pragma unroll
      for (int rr = 0; rr < 4; ++rr) {
        bb[rr] = bias[gc0 + rr];
#pragma unroll
        for (int k = 0; k < 10; ++k) wv[rr][k] = w2[(gc0 + rr) * 10 + k];
      }
#pragma unroll
      for (int i = 0; i < 4; ++i) {
        int gr = tm + wm + i * 16 + l15;
        size_t sidx = (((size_t)b * 8 + i * 2 + j) * 512 + tid) * 4;
        f32x4 old = *(const f32x4*)(statef + sidx);
        f32x4 nv; u16x4 sb;
#pragma unroll
        for (int rr = 0; rr < 4; ++rr) {
          float ex = bb[rr];
#pragma unroll
          for (int k = 0; k < 10; ++k) ex += s3v[i][k] * wv[rr][k];
          float pre = acc[i][j][rr] + ex;
          float o = old[rr];
          float sg = sigm(o);
          float n = o - SS * (sg * (1.0f - sg) * pre - o);
          nv[rr] = n; sb[rr] = f2bf(sigm(n));
        }
        *(f32x4*)(statef + sidx) = nv;
        *(u16x4*)(sigb + (size_t)gr * N + gc0) = sb;
      }
    }
  }
}

// ---------------------------------------------------------------------------
// output-layer update: pre[m][n] = sum_k sig(s2_new[m][k]) * w2[k*10+n] + b2[n]
// 16 rows per block, 16 lanes per row, bf16x8 vector loads, shuffle-reduce.
// ---------------------------------------------------------------------------
__global__ void k_out(const u16* __restrict__ sigs2b, const float* __restrict__ w2,
                      const float* __restrict__ b2, float* __restrict__ s3f,
                      float* __restrict__ sigs3f, float* __restrict__ outOrNull) {
  int tid = threadIdx.x;
  int r = tid >> 4, l16 = tid & 15;
  int row = blockIdx.x * 16 + r;
  float acc[10] = {};
  const u16* arow = sigs2b + (size_t)row * 2048;
  for (int kb = l16; kb < 256; kb += 16) {  // 8 u16 per chunk, 16B coalesced
    u16x4 v0 = *(const u16x4*)(arow + kb * 8);
    u16x4 v1 = *(const u16x4*)(arow + kb * 8 + 4);
    float a[8];
#pragma unroll
    for (int e = 0; e < 4; ++e) { a[e] = bf2f(v0[e]); a[e + 4] = bf2f(v1[e]); }
    const float* wr = w2 + (size_t)kb * 80;
#pragma unroll
    for (int e = 0; e < 8; ++e)
#pragma unroll
      for (int n = 0; n < 10; ++n) acc[n] += a[e] * wr[e * 10 + n];
  }
#pragma unroll
  for (int m = 1; m < 16; m <<= 1)
#pragma unroll
    for (int n = 0; n < 10; ++n) acc[n] += __shfl_xor(acc[n], m, 64);
  if (l16 < 10) {
    float pre = 0.0f;
#pragma unroll
    for (int n = 0; n < 10; ++n)
      if (l16 == n) pre = acc[n];
    pre += b2[l16];
    size_t idx = (size_t)row * 10 + l16;
    float old = s3f[idx];
    float sg = sigm(old);
    float nv = old - SS * (sg * (1.0f - sg) * pre - old);
    s3f[idx] = nv;
    sigs3f[idx] = sigm(nv);
    if (outOrNull) outOrNull[idx] = nv;
  }
}

// ---------------------------------------------------------------------------
extern "C" void kernel_launch(void* const* d_in, const int* in_sizes, int n_in,
                              void* d_out, int out_size, void* d_ws, size_t ws_size,
                              hipStream_t stream) {
  const float* x  = (const float*)d_in[0];
  const float* w0 = (const float*)d_in[1];  // 1024 x 2048
  const float* w1 = (const float*)d_in[2];  // 2048 x 2048
  const float* w2 = (const float*)d_in[3];  // 2048 x 10
  const float* b0 = (const float*)d_in[4];
  const float* b1 = (const float*)d_in[5];
  const float* b2 = (const float*)d_in[6];
  const float* s1 = (const float*)d_in[7];
  const float* s2 = (const float*)d_in[8];
  const float* s3 = (const float*)d_in[9];
  float* out = (float*)d_out;

  uint8_t* p = (uint8_t*)d_ws;
  auto alloc = [&](size_t bytes) {
    uint8_t* r = p;
    p += (bytes + 255) & ~(size_t)255;
    return r;
  };
  float* s1f    = (float*)alloc(4096ull * 2048 * 4);  // swizzle-resident
  float* s2f    = (float*)alloc(4096ull * 2048 * 4);  // swizzle-resident
  u16*   addcb  = (u16*)alloc(4096ull * 2048 * 2);    // swizzle-resident
  u16*   sigs1b = (u16*)alloc(4096ull * 2048 * 2);    // row-major
  u16*   sigs2b = (u16*)alloc(4096ull * 2048 * 2);    // row-major
  u16*   sigxb  = (u16*)alloc(4096ull * 1024 * 2);
  u16*   w1b    = (u16*)alloc(2048ull * 2048 * 2);    // Bt-layout for B = w1^T
  u16*   w1tb   = (u16*)alloc(2048ull * 2048 * 2);    // Bt-layout for B = w1
  u16*   w0tb   = (u16*)alloc(2048ull * 1024 * 2);    // Bt-layout for B = w0
  float* s3f    = (float*)alloc(4096ull * 10 * 4);
  float* sigs3f = (float*)alloc(4096ull * 10 * 4);
  (void)ws_size; (void)in_sizes; (void)n_in; (void)out_size;

  auto grid = [](int n) { int g = (n + 255) / 256; return g > 2048 ? 2048 : g; };

  // one-time prep (re-done every call: poison-safe, deterministic)
  k_prep<<<grid(4096 * 1024), 256, 0, stream>>>(x, nullptr, nullptr, sigxb, nullptr, 4096 * 1024);
  k_prep<<<grid(2048 * 2048), 256, 0, stream>>>(w1, nullptr, nullptr, nullptr, w1b, 2048 * 2048);
  k_prep<<<grid(4096 * 2048), 256, 0, stream>>>(s2, nullptr, nullptr, sigs2b, nullptr, 4096 * 2048);
  k_prep<<<grid(40960), 256, 0, stream>>>(s3, s3f, sigs3f, nullptr, nullptr, 40960);
  k_init_state<<<512, 512, 0, stream>>>(s1, s1f);
  k_init_state<<<512, 512, 0, stream>>>(s2, s2f);
  k_transpose_bf16<<<dim3(1024 / 32, 2048 / 32), 256, 0, stream>>>(w0, w0tb, 1024, 2048);
  k_transpose_bf16<<<dim3(2048 / 32, 2048 / 32), 256, 0, stream>>>(w1, w1tb, 2048, 2048);

  // addcb = bf16(sig(x) @ w0 + b0)   (M=4096, N=2048, K=1024) — loop-invariant
  k_gemm<0><<<512, 512, 0, stream>>>(sigxb, w0tb, 4096, 2048, 1024,
                                     nullptr, b0, nullptr, nullptr, nullptr, addcb);

  for (int t = 0; t < 20; ++t) {
    // s1 update: pre = (sigxw0 + b0) + sig(s2)@w1^T
    k_gemm<1><<<512, 512, 0, stream>>>(sigs2b, w1b, 4096, 2048, 2048,
                                       addcb, nullptr, nullptr, nullptr, s1f, sigs1b);
    // s2 update: pre = sig(s1_new)@w1 + sig(s3)@w2^T + b1
    k_gemm<2><<<512, 512, 0, stream>>>(sigs1b, w1tb, 4096, 2048, 2048,
                                       nullptr, b1, sigs3f, w2, s2f, sigs2b);
    // s3 update: pre = sig(s2_new)@w2 + b2
    k_out<<<256, 256, 0, stream>>>(sigs2b, w2, b2, s3f, sigs3f, (t == 19) ? out : nullptr);
  }
}